// Round 10
// baseline (1484.235 us; speedup 1.0000x reference)
//
#include <hip/hip_runtime.h>
#include <cstdint>
#include <cstddef>

#define NEG_SLOPE 0.2f
#define BN_EPS 1e-5f
#define BK_SHIFT 6          // 64 nodes per bucket
#define MAXBK 2048          // supports N <= 131072
#define CHUNK 8192          // edges per binning block
#define CAP 2048            // slots per bucket (mean fill ~1088, +30 sigma)

typedef _Float16 half4 __attribute__((ext_vector_type(4)));

// ---------------------------------------------------------------------------
// K0: fold b1 + BN(eval) into per-channel scale/shift, zero bucket cursors.
// ---------------------------------------------------------------------------
__global__ void prep_kernel(const float* __restrict__ b1,
                            const float* __restrict__ bn_gamma,
                            const float* __restrict__ bn_beta,
                            const float* __restrict__ bn_mean,
                            const float* __restrict__ bn_var,
                            float* __restrict__ pre0,
                            float* __restrict__ pre1,
                            int* __restrict__ bucket_cursor) {
    int t = threadIdx.x;            // 512 threads
    if (t < 128) {
        float sc = rsqrtf(bn_var[t] + BN_EPS) * bn_gamma[t];
        pre0[t] = sc;
        pre1[t] = (b1[t] - bn_mean[t]) * sc + bn_beta[t];
    }
    for (int i = t; i < MAXBK; i += 512) bucket_cursor[i] = 0;
}

// ---------------------------------------------------------------------------
// K1 (fused): blockIdx < NCH  -> binning pass; else gemm1.
// bin: LDS histogram over 64-node buckets -> one reservation per
// (block,bucket) -> compact packed writes  word = (dst&63)<<24 | src.
// gemm: h0[N,128] = x@W1 (fp16 store), fused as1/ad1 epilogue.
// ---------------------------------------------------------------------------
__global__ void gemm_bin_kernel(// gemm args
                                const float* __restrict__ x,
                                const float* __restrict__ W1,
                                const float* __restrict__ att_s,
                                const float* __restrict__ att_d,
                                _Float16* __restrict__ h0,
                                float* __restrict__ as1,
                                float* __restrict__ ad1,
                                int N,
                                // bin args
                                const int* __restrict__ ei, int E, int NBK,
                                int* __restrict__ bucket_cursor,
                                unsigned int* __restrict__ binned,
                                int NCH) {
    __shared__ int cnt[MAXBK];
    __shared__ int gstart[MAXBK];
    __shared__ int cur[MAXBK];
    if (blockIdx.x < NCH) {
        int T = E + N;
        for (int b = threadIdx.x; b < NBK; b += 256) { cnt[b] = 0; cur[b] = 0; }
        __syncthreads();
        int base = blockIdx.x * CHUNK;
        for (int k = 0; k < CHUNK; k += 256) {
            int i = base + k + threadIdx.x;
            if (i < T) {
                int dst = (i < E) ? ei[E + i] : (i - E);
                atomicAdd(&cnt[dst >> BK_SHIFT], 1);
            }
        }
        __syncthreads();
        for (int b = threadIdx.x; b < NBK; b += 256) {
            int c = cnt[b];
            if (c) gstart[b] = atomicAdd(&bucket_cursor[b], c);
        }
        __syncthreads();
        for (int k = 0; k < CHUNK; k += 256) {
            int i = base + k + threadIdx.x;
            if (i < T) {
                int src, dst;
                if (i < E) { src = ei[i]; dst = ei[E + i]; }
                else       { src = i - E; dst = src; }
                int b = dst >> BK_SHIFT;
                int lp = gstart[b] + atomicAdd(&cur[b], 1);
                if (lp < CAP)   // overflow guard (statistically impossible)
                    binned[(size_t)b * CAP + lp] =
                        (unsigned int)src | ((unsigned int)(dst & 63) << 24);
            }
        }
        return;
    }
    // ----- gemm path: 4 nodes per thread (W1 reuse x4), fp16 h0 store
    int bid = blockIdx.x - NCH;
    int c = threadIdx.x & 127;
    int pair = __builtin_amdgcn_readfirstlane(threadIdx.x >> 7);
    int n0 = (bid * 2 + pair) * 4;
    if (n0 >= N) return;
    float acc[4] = {0.f, 0.f, 0.f, 0.f};
    const float* __restrict__ xr = x + (size_t)n0 * 64;
    int nn = N - n0; if (nn > 4) nn = 4;
    if (nn == 4) {
#pragma unroll
        for (int k = 0; k < 64; ++k) {
            float w = W1[k * 128 + c];
            acc[0] = fmaf(xr[k],       w, acc[0]);
            acc[1] = fmaf(xr[64 + k],  w, acc[1]);
            acc[2] = fmaf(xr[128 + k], w, acc[2]);
            acc[3] = fmaf(xr[192 + k], w, acc[3]);
        }
    } else {
        for (int i = 0; i < nn; ++i)
            for (int k = 0; k < 64; ++k)
                acc[i] = fmaf(xr[i * 64 + k], W1[k * 128 + c], acc[i]);
    }
    float asc = att_s[c], adc = att_d[c];
    int head = c >> 5;
#pragma unroll
    for (int i = 0; i < 4; ++i) {
        if (i >= nn) break;
        int n = n0 + i;
        h0[(size_t)n * 128 + c] = (_Float16)acc[i];
        float s = acc[i] * asc;
        float d = acc[i] * adc;
#pragma unroll
        for (int off = 16; off >= 1; off >>= 1) {
            s += __shfl_xor(s, off);
            d += __shfl_xor(d, off);
        }
        if ((threadIdx.x & 31) == 0) {
            as1[(size_t)n * 4 + head] = s;
            ad1[(size_t)n * 4 + head] = d;
        }
    }
}

// ---------------------------------------------------------------------------
// K2: layer-1 gather, bucket-resident. One block per 64-node bucket.
// Streams the bucket's binned entries; per edge, a 32-lane group computes w
// (R5-proven body: redundant exp per 8-lane head group, half4 h0 load) and
// ds_add_f32's its 4 channels into LDS acc[dl][.]. No csr / row_ptr at all.
// Epilogue: 4 threads per node -> pre0/pre1 + ELU + dot(W2) -> h2.
// ---------------------------------------------------------------------------
__global__ void gather1_kernel(const unsigned int* __restrict__ binned,
                               const int* __restrict__ bucket_cursor,
                               const half4* __restrict__ h0,
                               const float* __restrict__ as1,
                               const float* __restrict__ ad1,
                               const float* __restrict__ pre0,
                               const float* __restrict__ pre1,
                               const float* __restrict__ W2,
                               float* __restrict__ h2, int N) {
    __shared__ float acc[64][132];   // +4 pad: decorrelate row bank sets
    __shared__ float den[64][4];
    int b = blockIdx.x;
    int tid = threadIdx.x;          // 256 threads
    int n0 = b << BK_SHIFT;
    int nr = N - n0; if (nr > 64) nr = 64;
    int tot = bucket_cursor[b];
    if (tot > CAP) tot = CAP;
    size_t base = (size_t)b * CAP;
    for (int i = tid; i < 64 * 132; i += 256) (&acc[0][0])[i] = 0.f;
    den[tid >> 2][tid & 3] = 0.f;
    __syncthreads();
    int lane = tid & 63;
    int wv   = tid >> 6;            // wave 0..3
    int sub  = lane & 31;           // half4 index within the 128-ch row
    int grp  = lane >> 5;           // which edge of the wave's pair
    int head = sub >> 3;
    for (int j = wv * 2 + grp; j < tot; j += 8) {
        unsigned int word = binned[base + j];
        int src = (int)(word & 0xFFFFFFu);
        int dl  = (int)(word >> 24);
        float as = as1[(size_t)src * 4 + head];
        float ad = ad1[(size_t)(n0 + dl) * 4 + head];
        float lg = as + ad;
        float l = fmaf(NEG_SLOPE, fminf(lg, 0.f), fmaxf(lg, 0.f));
        float w = __expf(l);
        half4 hv = h0[(size_t)src * 32 + sub];
        atomicAdd(&acc[dl][sub * 4 + 0], w * (float)hv.x);
        atomicAdd(&acc[dl][sub * 4 + 1], w * (float)hv.y);
        atomicAdd(&acc[dl][sub * 4 + 2], w * (float)hv.z);
        atomicAdd(&acc[dl][sub * 4 + 3], w * (float)hv.w);
        if ((sub & 7) == 0) atomicAdd(&den[dl][head], w);
    }
    __syncthreads();
    // epilogue: thread quad (node = tid>>2, part = tid&3) covers 32 channels
    int node = tid >> 2;
    int part = tid & 3;             // == head of channels part*32..part*32+31
    float t = 0.f;
    if (node < nr) {
        float inv = 1.f / (den[node][part] + 1e-16f);
        int c0 = part * 32;
#pragma unroll
        for (int k = 0; k < 32; ++k) {
            int c = c0 + k;
            float v = fmaf(acc[node][c] * inv, pre0[c], pre1[c]);
            v = v > 0.f ? v : expm1f(v);    // ELU (alpha=1)
            t = fmaf(v, W2[c], t);
        }
    }
    t += __shfl_xor(t, 1);
    t += __shfl_xor(t, 2);
    if (part == 0 && node < nr) h2[n0 + node] = t;
}

// ---------------------------------------------------------------------------
// K3: layer-2 gather, bucket-resident. One block per bucket; one thread per
// edge; num/den accumulate in LDS; h2 bucket row staged in LDS.
// ---------------------------------------------------------------------------
__global__ void gather2_kernel(const unsigned int* __restrict__ binned,
                               const int* __restrict__ bucket_cursor,
                               const float* __restrict__ h2,
                               const float* __restrict__ att_s2,
                               const float* __restrict__ att_d2,
                               const float* __restrict__ b2,
                               float* __restrict__ out, int N) {
    __shared__ float num[64];
    __shared__ float den[64];
    __shared__ float hloc[64];
    int b = blockIdx.x;
    int tid = threadIdx.x;          // 256 threads
    int n0 = b << BK_SHIFT;
    int nr = N - n0; if (nr > 64) nr = 64;
    int tot = bucket_cursor[b];
    if (tot > CAP) tot = CAP;
    size_t base = (size_t)b * CAP;
    if (tid < 64) {
        num[tid] = 0.f;
        den[tid] = 0.f;
        if (tid < nr) hloc[tid] = h2[n0 + tid];
    }
    __syncthreads();
    float a_s = att_s2[0];
    float a_d = att_d2[0];
    for (int j = tid; j < tot; j += 256) {
        unsigned int word = binned[base + j];
        int src = (int)(word & 0xFFFFFFu);
        int dl  = (int)(word >> 24);
        float hs = h2[src];
        float lg = fmaf(hs, a_s, hloc[dl] * a_d);
        float l = fmaf(NEG_SLOPE, fminf(lg, 0.f), fmaxf(lg, 0.f));
        float w = __expf(l);
        atomicAdd(&num[dl], w * hs);
        atomicAdd(&den[dl], w);
    }
    __syncthreads();
    if (tid < nr) out[n0 + tid] = num[tid] / (den[tid] + 1e-16f) + b2[0];
}

extern "C" void kernel_launch(void* const* d_in, const int* in_sizes, int n_in,
                              void* d_out, int out_size, void* d_ws, size_t ws_size,
                              hipStream_t stream) {
    const float* x     = (const float*)d_in[0];
    const int*   ei    = (const int*)  d_in[1];
    const float* W1    = (const float*)d_in[2];
    const float* atts1 = (const float*)d_in[3];
    const float* attd1 = (const float*)d_in[4];
    const float* b1    = (const float*)d_in[5];
    const float* W2    = (const float*)d_in[6];
    const float* atts2 = (const float*)d_in[7];
    const float* attd2 = (const float*)d_in[8];
    const float* b2    = (const float*)d_in[9];
    const float* bn_g  = (const float*)d_in[10];
    const float* bn_b  = (const float*)d_in[11];
    const float* bn_m  = (const float*)d_in[12];
    const float* bn_v  = (const float*)d_in[13];

    const int N = in_sizes[0] / 64;     // 100000
    const int E = in_sizes[1] / 2;      // 1600000
    const int T = E + N;
    const int NBK = (N + 63) >> BK_SHIFT;             // 64-node buckets
    const int NCH = (T + CHUNK - 1) / CHUNK;          // binning blocks
    const int NGB = (N + 7) / 8;                      // gemm blocks

    // workspace layout (manual alignment)
    char* p = (char*)d_ws;
    auto alloc = [&](size_t bytes, size_t align) -> void* {
        uintptr_t q = ((uintptr_t)p + align - 1) & ~(uintptr_t)(align - 1);
        p = (char*)(q + bytes);
        return (void*)q;
    };
    _Float16* h0      = (_Float16*)alloc((size_t)N * 128 * 2, 16);
    float* as1        = (float*)alloc((size_t)N * 4 * 4, 16);
    float* ad1        = (float*)alloc((size_t)N * 4 * 4, 16);
    float* h2         = (float*)alloc((size_t)N * 4, 16);
    float* pre0       = (float*)alloc(128 * 4, 16);
    float* pre1       = (float*)alloc(128 * 4, 16);
    int*   bucket_cur = (int*)alloc((size_t)MAXBK * 4, 16);
    unsigned int* binned = (unsigned int*)alloc((size_t)NBK * CAP * 4, 16);

    prep_kernel<<<1, 512, 0, stream>>>(b1, bn_g, bn_b, bn_m, bn_v,
                                       pre0, pre1, bucket_cur);

    gemm_bin_kernel<<<NCH + NGB, 256, 0, stream>>>(
        x, W1, atts1, attd1, h0, as1, ad1, N,
        ei, E, NBK, bucket_cur, binned, NCH);

    gather1_kernel<<<NBK, 256, 0, stream>>>(
        binned, bucket_cur, (const half4*)h0, as1, ad1, pre0, pre1,
        W2, h2, N);

    gather2_kernel<<<NBK, 256, 0, stream>>>(
        binned, bucket_cur, h2, atts2, attd2, b2, (float*)d_out, N);
}

// Round 11
// 274.628 us; speedup vs baseline: 5.4045x; 5.4045x over previous
//
#include <hip/hip_runtime.h>
#include <cstdint>
#include <cstddef>

#define NEG_SLOPE 0.2f
#define BN_EPS 1e-5f
#define BK_SHIFT 8          // 256 nodes per bucket
#define MAXBK 512           // supports N <= 131072
#define CHUNK 8192          // edges per binning block
#define CAP 8192            // slots per bucket (mean fill 4352, +58 sigma)

typedef _Float16 half4 __attribute__((ext_vector_type(4)));

// ---------------------------------------------------------------------------
// K0: fold b1 + BN(eval) into per-channel scale/shift, zero bucket cursors.
// ---------------------------------------------------------------------------
__global__ void prep_kernel(const float* __restrict__ b1,
                            const float* __restrict__ bn_gamma,
                            const float* __restrict__ bn_beta,
                            const float* __restrict__ bn_mean,
                            const float* __restrict__ bn_var,
                            float* __restrict__ pre0,
                            float* __restrict__ pre1,
                            int* __restrict__ bucket_cursor) {
    int t = threadIdx.x;            // 512 threads
    if (t < 128) {
        float sc = rsqrtf(bn_var[t] + BN_EPS) * bn_gamma[t];
        pre0[t] = sc;
        pre1[t] = (b1[t] - bn_mean[t]) * sc + bn_beta[t];
    }
    if (t < MAXBK) bucket_cursor[t] = 0;
}

// ---------------------------------------------------------------------------
// K1 (fused): blockIdx < NCH  -> binning pass; else gemm1.
// bin: LDS histogram over 256-node buckets -> one reservation per
// (block,bucket) -> compact packed writes  word = (dst&255)<<24 | src.
// gemm: h0[N,128] = x@W1 (fp16 store), fused as1/ad1 epilogue.
// (R9-proven: fusing hides the GEMM behind the bin pass.)
// ---------------------------------------------------------------------------
__global__ void gemm_bin_kernel(// gemm args
                                const float* __restrict__ x,
                                const float* __restrict__ W1,
                                const float* __restrict__ att_s,
                                const float* __restrict__ att_d,
                                _Float16* __restrict__ h0,
                                float* __restrict__ as1,
                                float* __restrict__ ad1,
                                int N,
                                // bin args
                                const int* __restrict__ ei, int E, int NBK,
                                int* __restrict__ bucket_cursor,
                                unsigned int* __restrict__ binned,
                                int NCH) {
    __shared__ int cnt[MAXBK];
    __shared__ int gstart[MAXBK];
    __shared__ int cur[MAXBK];
    if (blockIdx.x < NCH) {
        int T = E + N;
        for (int b = threadIdx.x; b < NBK; b += 256) { cnt[b] = 0; cur[b] = 0; }
        __syncthreads();
        int base = blockIdx.x * CHUNK;
        for (int k = 0; k < CHUNK; k += 256) {
            int i = base + k + threadIdx.x;
            if (i < T) {
                int dst = (i < E) ? ei[E + i] : (i - E);
                atomicAdd(&cnt[dst >> BK_SHIFT], 1);
            }
        }
        __syncthreads();
        for (int b = threadIdx.x; b < NBK; b += 256) {
            int c = cnt[b];
            if (c) gstart[b] = atomicAdd(&bucket_cursor[b], c);
        }
        __syncthreads();
        for (int k = 0; k < CHUNK; k += 256) {
            int i = base + k + threadIdx.x;
            if (i < T) {
                int src, dst;
                if (i < E) { src = ei[i]; dst = ei[E + i]; }
                else       { src = i - E; dst = src; }
                int b = dst >> BK_SHIFT;
                int lp = gstart[b] + atomicAdd(&cur[b], 1);
                if (lp < CAP)   // overflow guard (statistically impossible)
                    binned[(size_t)b * CAP + lp] =
                        (unsigned int)src | ((unsigned int)(dst & 255) << 24);
            }
        }
        return;
    }
    // ----- gemm path: 4 nodes per thread (W1 reuse x4), fp16 h0 store
    int bid = blockIdx.x - NCH;
    int c = threadIdx.x & 127;
    int pair = __builtin_amdgcn_readfirstlane(threadIdx.x >> 7);
    int n0 = (bid * 2 + pair) * 4;
    if (n0 >= N) return;
    float acc[4] = {0.f, 0.f, 0.f, 0.f};
    const float* __restrict__ xr = x + (size_t)n0 * 64;
    int nn = N - n0; if (nn > 4) nn = 4;
    if (nn == 4) {
#pragma unroll
        for (int k = 0; k < 64; ++k) {
            float w = W1[k * 128 + c];
            acc[0] = fmaf(xr[k],       w, acc[0]);
            acc[1] = fmaf(xr[64 + k],  w, acc[1]);
            acc[2] = fmaf(xr[128 + k], w, acc[2]);
            acc[3] = fmaf(xr[192 + k], w, acc[3]);
        }
    } else {
        for (int i = 0; i < nn; ++i)
            for (int k = 0; k < 64; ++k)
                acc[i] = fmaf(xr[i * 64 + k], W1[k * 128 + c], acc[i]);
    }
    float asc = att_s[c], adc = att_d[c];
    int head = c >> 5;
#pragma unroll
    for (int i = 0; i < 4; ++i) {
        if (i >= nn) break;
        int n = n0 + i;
        h0[(size_t)n * 128 + c] = (_Float16)acc[i];
        float s = acc[i] * asc;
        float d = acc[i] * adc;
#pragma unroll
        for (int off = 16; off >= 1; off >>= 1) {
            s += __shfl_xor(s, off);
            d += __shfl_xor(d, off);
        }
        if ((threadIdx.x & 31) == 0) {
            as1[(size_t)n * 4 + head] = s;
            ad1[(size_t)n * 4 + head] = d;
        }
    }
}

// ---------------------------------------------------------------------------
// K2: per-bucket finalize (R8-proven). One block per bucket: LDS per-node
// count -> scan -> row_beg/row_end, then scatter src into the bucket's
// contiguous region of csr_src.
// ---------------------------------------------------------------------------
__global__ void csr_kernel(const unsigned int* __restrict__ binned,
                           const int* __restrict__ bucket_cursor,
                           int N,
                           int* __restrict__ row_beg,
                           int* __restrict__ row_end,
                           int* __restrict__ csr_src) {
    __shared__ int cnt[256];
    __shared__ int loc[256];
    __shared__ int cur[256];
    int b = blockIdx.x;
    int tid = threadIdx.x;          // 256 threads
    int n0 = b << BK_SHIFT;
    int nr = N - n0; if (nr > 256) nr = 256;
    int tot = bucket_cursor[b];
    if (tot > CAP) tot = CAP;
    size_t base = (size_t)b * CAP;
    cnt[tid] = 0;
    __syncthreads();
    for (int j = tid; j < tot; j += 256) {
        atomicAdd(&cnt[binned[base + j] >> 24], 1);
    }
    __syncthreads();
    int v = cnt[tid];
    loc[tid] = v;
    __syncthreads();
    for (int off = 1; off < 256; off <<= 1) {
        int t = (tid >= off) ? loc[tid - off] : 0;
        __syncthreads();
        loc[tid] += t;
        __syncthreads();
    }
    int excl = loc[tid] - v;
    cur[tid] = excl;
    if (tid < nr) {
        row_beg[n0 + tid] = (int)base + excl;
        row_end[n0 + tid] = (int)base + excl + v;
    }
    __syncthreads();
    for (int j = tid; j < tot; j += 256) {
        unsigned int w = binned[base + j];
        int pos = atomicAdd(&cur[w >> 24], 1);
        csr_src[base + pos] = (int)(w & 0xFFFFFFu);
    }
}

// ---------------------------------------------------------------------------
// K3: layer-1 gather + finalize — the R5/R7-PROVEN body, unchanged.
// ONE WAVE per dst node (block 256 = 4 nodes); 2x32-lane edge-groups;
// half4 (8B dwordx2) h0 loads; redundant-but-overlappable exp per 8-lane
// head group; register accumulators; shfl combine; prefolded pre0/pre1.
// (R6 half8/16-lane, R9 two-phase LDS, R10 LDS-atomic variants all
// regressed — do not restructure this loop.)
// ---------------------------------------------------------------------------
__global__ void gather1_kernel(const int* __restrict__ row_beg,
                               const int* __restrict__ row_end,
                               const int* __restrict__ csr_src,
                               const half4* __restrict__ h0,
                               const float* __restrict__ as1,
                               const float* __restrict__ ad1,
                               const float* __restrict__ pre0,
                               const float* __restrict__ pre1,
                               const float* __restrict__ W2,
                               float* __restrict__ h2, int N) {
    int n = blockIdx.x * 4 + (threadIdx.x >> 6);
    if (n >= N) return;
    int lane = threadIdx.x & 63;
    int sub  = lane & 31;           // half4 index within the 128-ch row
    int grp  = lane >> 5;           // which edge of the pair
    int head = sub >> 3;            // channels 4*sub..4*sub+3 are in this head
    float ad = ad1[(size_t)n * 4 + head];
    int beg = row_beg[n];
    int end = row_end[n];
    float4 acc = make_float4(0.f, 0.f, 0.f, 0.f);
    float den = 0.f;
#pragma unroll 2
    for (int j = beg + grp; j < end; j += 2) {
        int src = csr_src[j];
        float as = as1[(size_t)src * 4 + head];
        float lg = as + ad;
        float l = fmaf(NEG_SLOPE, fminf(lg, 0.f), fmaxf(lg, 0.f));
        float w = __expf(l);
        half4 hv = h0[(size_t)src * 32 + sub];
        acc.x = fmaf(w, (float)hv.x, acc.x);
        acc.y = fmaf(w, (float)hv.y, acc.y);
        acc.z = fmaf(w, (float)hv.z, acc.z);
        acc.w = fmaf(w, (float)hv.w, acc.w);
        den += w;
    }
    acc.x += __shfl_xor(acc.x, 32);
    acc.y += __shfl_xor(acc.y, 32);
    acc.z += __shfl_xor(acc.z, 32);
    acc.w += __shfl_xor(acc.w, 32);
    den   += __shfl_xor(den, 32);
    float inv = 1.f / (den + 1e-16f);
    int c = sub * 4;
    float v0 = fmaf(acc.x * inv, pre0[c],     pre1[c]);
    float v1 = fmaf(acc.y * inv, pre0[c + 1], pre1[c + 1]);
    float v2 = fmaf(acc.z * inv, pre0[c + 2], pre1[c + 2]);
    float v3 = fmaf(acc.w * inv, pre0[c + 3], pre1[c + 3]);
    v0 = v0 > 0.f ? v0 : expm1f(v0);
    v1 = v1 > 0.f ? v1 : expm1f(v1);
    v2 = v2 > 0.f ? v2 : expm1f(v2);
    v3 = v3 > 0.f ? v3 : expm1f(v3);
    float t = v0 * W2[c] + v1 * W2[c + 1] + v2 * W2[c + 2] + v3 * W2[c + 3];
#pragma unroll
    for (int off = 16; off >= 1; off >>= 1) t += __shfl_xor(t, off);
    if (lane == 0) h2[n] = t;
}

// ---------------------------------------------------------------------------
// K4: layer-2 gather (R7-proven). 16-lane group per dst node
// (block 256 = 16 nodes); mean degree ~17 -> lanes ~fully utilized.
// ---------------------------------------------------------------------------
__global__ void gather2_kernel(const int* __restrict__ row_beg,
                               const int* __restrict__ row_end,
                               const int* __restrict__ csr_src,
                               const float* __restrict__ h2,
                               const float* __restrict__ att_s2,
                               const float* __restrict__ att_d2,
                               const float* __restrict__ b2,
                               float* __restrict__ out, int N) {
    int n = blockIdx.x * 16 + (threadIdx.x >> 4);
    if (n >= N) return;
    int lane = threadIdx.x & 15;
    int beg = row_beg[n];
    int end = row_end[n];
    float a_s = att_s2[0];
    float a_d = att_d2[0];
    float hd = h2[n];
    float num = 0.f, den = 0.f;
    for (int j = beg + lane; j < end; j += 16) {
        int src = csr_src[j];
        float hs = h2[src];
        float lg = hs * a_s + hd * a_d;
        float l = fmaf(NEG_SLOPE, fminf(lg, 0.f), fmaxf(lg, 0.f));
        float w = __expf(l);
        num += w * hs;
        den += w;
    }
#pragma unroll
    for (int off = 8; off >= 1; off >>= 1) {
        num += __shfl_xor(num, off);
        den += __shfl_xor(den, off);
    }
    if (lane == 0) out[n] = num / (den + 1e-16f) + b2[0];
}

extern "C" void kernel_launch(void* const* d_in, const int* in_sizes, int n_in,
                              void* d_out, int out_size, void* d_ws, size_t ws_size,
                              hipStream_t stream) {
    const float* x     = (const float*)d_in[0];
    const int*   ei    = (const int*)  d_in[1];
    const float* W1    = (const float*)d_in[2];
    const float* atts1 = (const float*)d_in[3];
    const float* attd1 = (const float*)d_in[4];
    const float* b1    = (const float*)d_in[5];
    const float* W2    = (const float*)d_in[6];
    const float* atts2 = (const float*)d_in[7];
    const float* attd2 = (const float*)d_in[8];
    const float* b2    = (const float*)d_in[9];
    const float* bn_g  = (const float*)d_in[10];
    const float* bn_b  = (const float*)d_in[11];
    const float* bn_m  = (const float*)d_in[12];
    const float* bn_v  = (const float*)d_in[13];

    const int N = in_sizes[0] / 64;     // 100000
    const int E = in_sizes[1] / 2;      // 1600000
    const int T = E + N;
    const int NBK = (N + 255) >> BK_SHIFT;            // 256-node buckets
    const int NCH = (T + CHUNK - 1) / CHUNK;          // binning blocks
    const int NGB = (N + 7) / 8;                      // gemm blocks

    // workspace layout (manual alignment)
    char* p = (char*)d_ws;
    auto alloc = [&](size_t bytes, size_t align) -> void* {
        uintptr_t q = ((uintptr_t)p + align - 1) & ~(uintptr_t)(align - 1);
        p = (char*)(q + bytes);
        return (void*)q;
    };
    _Float16* h0      = (_Float16*)alloc((size_t)N * 128 * 2, 16);
    float* as1        = (float*)alloc((size_t)N * 4 * 4, 16);
    float* ad1        = (float*)alloc((size_t)N * 4 * 4, 16);
    float* h2         = (float*)alloc((size_t)N * 4, 16);
    float* pre0       = (float*)alloc(128 * 4, 16);
    float* pre1       = (float*)alloc(128 * 4, 16);
    int*   row_beg    = (int*)alloc((size_t)N * 4, 16);
    int*   row_end    = (int*)alloc((size_t)N * 4, 16);
    int*   bucket_cur = (int*)alloc((size_t)MAXBK * 4, 16);
    unsigned int* binned = (unsigned int*)alloc((size_t)NBK * CAP * 4, 16);
    int*   csr_src    = (int*)alloc((size_t)NBK * CAP * 4, 16);

    prep_kernel<<<1, 512, 0, stream>>>(b1, bn_g, bn_b, bn_m, bn_v,
                                       pre0, pre1, bucket_cur);

    gemm_bin_kernel<<<NCH + NGB, 256, 0, stream>>>(
        x, W1, atts1, attd1, h0, as1, ad1, N,
        ei, E, NBK, bucket_cur, binned, NCH);

    csr_kernel<<<NBK, 256, 0, stream>>>(binned, bucket_cur, N,
                                        row_beg, row_end, csr_src);

    gather1_kernel<<<(N + 3) / 4, 256, 0, stream>>>(
        row_beg, row_end, csr_src, (const half4*)h0, as1, ad1, pre0, pre1,
        W2, h2, N);

    gather2_kernel<<<(N + 15) / 16, 256, 0, stream>>>(
        row_beg, row_end, csr_src, h2, atts2, attd2, b2, (float*)d_out, N);
}